// Round 4
// baseline (73.245 us; speedup 1.0000x reference)
//
#include <hip/hip_runtime.h>
#include <hip/hip_fp16.h>

// Problem constants (B, L, C, H, W) = (2, 48, 8, 48, 48)
constexpr int B = 2, L = 48, C = 8, H = 48, W = 48;
constexpr int HW = H * W;   // 2304

constexpr int QD = 49;          // quad grid dim: corner coords in [-1, 47]
constexpr int QN = QD * QD;     // 2401 quads per (b,l)

constexpr int PPB = 64;     // pixels per block
constexpr int SL  = 4;      // k-slices per block (threads = PPB*SL = 256)

// ---------------------------------------------------------------------------
// Kernel 1: cumulative sum of flows along L, packed as float2 (B, L, HW, 2)
// so the per-k coordinate load is one coalesced 8B load. fp32 scan, same
// accumulation order as jnp.cumsum.
// ---------------------------------------------------------------------------
__global__ void cumsum_kernel(const float* __restrict__ flows, float* __restrict__ cum2) {
    int tid = blockIdx.x * blockDim.x + threadIdx.x;
    if (tid >= B * 2 * HW) return;
    int pix  = tid % HW;
    int comp = (tid / HW) & 1;
    int b    = tid / (2 * HW);
    const float* src = flows + (size_t)b * L * 2 * HW + (size_t)comp * HW + pix;
    float*       dst = cum2  + ((size_t)b * L * HW + pix) * 2 + comp;
    float acc = 0.0f;
#pragma unroll
    for (int l = 0; l < L; ++l) {
        acc += src[(size_t)l * 2 * HW];
        dst[(size_t)l * HW * 2] = acc;
    }
}

// ---------------------------------------------------------------------------
// Kernel 2a (quad path): build 64B quad records. quads[bl][qy+1][qx+1] holds
// the 2x2 bilinear footprint with corner (qy,qx), 8 fp16 channels per tap:
//   slot0=(y0,x0) slot1=(y0,x1) slot2=(y1,x0) slot3=(y1,x1), indices clamped.
// Clamped-duplicate slots are always paired with zero validity weights in the
// main kernel, so their values are harmless.
// ---------------------------------------------------------------------------
__global__ void quad_build_kernel(const float* __restrict__ images, __half* __restrict__ quads) {
    int tid = blockIdx.x * blockDim.x + threadIdx.x;
    if (tid >= B * L * QN) return;
    int q  = tid % QN;
    int bl = tid / QN;
    int qx = q % QD - 1;            // [-1, 47]
    int qy = q / QD - 1;            // [-1, 47]
    int x0 = max(qx, 0),     x1 = min(qx + 1, W - 1);
    int y0 = max(qy, 0),     y1 = min(qy + 1, H - 1);
    int o00 = y0 * W + x0, o10 = y0 * W + x1;
    int o01 = y1 * W + x0, o11 = y1 * W + x1;
    const float* src = images + (size_t)bl * C * HW;
    __half hbuf[32];
#pragma unroll
    for (int c = 0; c < C; ++c) {
        const float* pc = src + (size_t)c * HW;
        hbuf[c]      = __float2half(pc[o00]);
        hbuf[8 + c]  = __float2half(pc[o10]);
        hbuf[16 + c] = __float2half(pc[o01]);
        hbuf[24 + c] = __float2half(pc[o11]);
    }
    float4* dst = reinterpret_cast<float4*>(quads + (size_t)tid * 32);
    const float4* s = reinterpret_cast<const float4*>(hbuf);
    dst[0] = s[0]; dst[1] = s[1]; dst[2] = s[2]; dst[3] = s[3];
}

// ---------------------------------------------------------------------------
// Kernel 2b (fallback path): images fp32 (B,L,C,H,W) -> fp16 channel-last.
// ---------------------------------------------------------------------------
__global__ void convert_kernel(const float* __restrict__ images, __half* __restrict__ imgH) {
    int tid = blockIdx.x * blockDim.x + threadIdx.x;
    if (tid >= B * L * HW) return;
    int pix = tid % HW;
    int bl  = tid / HW;
    const float* src = images + (size_t)bl * C * HW + pix;
    __half h[C];
#pragma unroll
    for (int c = 0; c < C; ++c) h[c] = __float2half(src[(size_t)c * HW]);
    float4* dst = reinterpret_cast<float4*>(imgH + ((size_t)bl * HW + pix) * C);
    *dst = *reinterpret_cast<float4*>(h);
}

// ---------------------------------------------------------------------------
// Shared per-sample coordinate math. Returns weights + quad corner.
// ---------------------------------------------------------------------------
struct SampleGeom {
    float w00, w10, w01, w11;
    int x0, y0;      // unclamped floor corner (x0 in [-1,47]; y0 unbounded)
};

__device__ __forceinline__ SampleGeom sample_geom(float base_gx_p1, float base_gy,
                                                  float relx, float rely) {
    // x wrap: remainder(base_gx + relx + 1, 2) in [0,2); exact ladder,
    // bit-identical to jnp.remainder for |v| < 8.
    float v = base_gx_p1 + relx;
    v = (v >= 2.0f) ? v - 2.0f : v;
    v = (v >= 2.0f) ? v - 2.0f : v;
    v = (v >= 2.0f) ? v - 2.0f : v;
    v = (v <  0.0f) ? v + 2.0f : v;
    v = (v <  0.0f) ? v + 2.0f : v;
    v = (v <  0.0f) ? v + 2.0f : v;

    float ix = (v * (float)W - 1.0f) * 0.5f;              // [-0.5, 47.5)
    float gy = base_gy + rely;
    float iy = ((gy + 1.0f) * (float)H - 1.0f) * 0.5f;

    float x0f = floorf(ix), y0f = floorf(iy);
    float wx1 = ix - x0f,   wy1 = iy - y0f;
    float wx0 = 1.0f - wx1, wy0 = 1.0f - wy1;

    // tap validity on the UNCLAMPED floored coords (matches reference)
    float vx0 = (x0f >= 0.0f  && x0f <= (float)(W - 1)) ? 1.0f : 0.0f;
    float vx1 = (x0f >= -1.0f && x0f <= (float)(W - 2)) ? 1.0f : 0.0f;
    float vy0 = (y0f >= 0.0f  && y0f <= (float)(H - 1)) ? 1.0f : 0.0f;
    float vy1 = (y0f >= -1.0f && y0f <= (float)(H - 2)) ? 1.0f : 0.0f;

    SampleGeom g;
    g.w00 = wx0 * wy0 * vx0 * vy0;
    g.w10 = wx1 * wy0 * vx1 * vy0;
    g.w01 = wx0 * wy1 * vx0 * vy1;
    g.w11 = wx1 * wy1 * vx1 * vy1;
    g.x0  = (int)x0f;
    g.y0  = (int)y0f;
    return g;
}

// ---------------------------------------------------------------------------
// Kernel 3 (quad path): main warp+scan. Block = 64 pixels x 4 k-slices.
// Each sample reads one 64B quad (4 x dwordx4 from a single cache line).
// ---------------------------------------------------------------------------
__global__ void warp_scan_quad(const float* __restrict__ cum2,
                               const __half* __restrict__ quads,
                               float* __restrict__ out) {
    const int p   = threadIdx.x & (PPB - 1);
    const int s   = threadIdx.x >> 6;
    const int pix = blockIdx.x * PPB + p;
    const int t   = L - 1 - blockIdx.y;
    const int b   = blockIdx.z;
    const int w   = pix % W;
    const int h   = pix / W;

    const float base_gx_p1 = (2 * w + 1) * (1.0f / W);
    const float base_gy    = (2 * h + 1) * (1.0f / H) - 1.0f;

    const float* cb = cum2 + ((size_t)b * L * HW + pix) * 2;
    const float2 ct = *reinterpret_cast<const float2*>(cb + (size_t)t * HW * 2);
    const float ctx = ct.x, cty = ct.y;

    float acc[C];
#pragma unroll
    for (int c = 0; c < C; ++c) acc[c] = 0.0f;

#pragma unroll 2
    for (int k = s; k <= t; k += SL) {
        const float2 ck = *reinterpret_cast<const float2*>(cb + (size_t)k * HW * 2);
        SampleGeom g = sample_geom(base_gx_p1, base_gy, ctx - ck.x, cty - ck.y);

        int qxi = g.x0 + 1;                              // [0,48]
        int qyi = min(max(g.y0, -1), H - 1) + 1;         // [0,48]
        const float4* eq = reinterpret_cast<const float4*>(
            quads + ((size_t)(b * L + k) * QN + (size_t)(qyi * QD + qxi)) * 32);
        float4 r00 = eq[0], r10 = eq[1], r01 = eq[2], r11 = eq[3];

        auto mix = [&](const float4& raw, float wgt) {
            const __half2* hc = reinterpret_cast<const __half2*>(&raw);
#pragma unroll
            for (int c = 0; c < 4; ++c) {
                float2 f = __half22float2(hc[c]);
                acc[2 * c]     += wgt * f.x;
                acc[2 * c + 1] += wgt * f.y;
            }
        };
        mix(r00, g.w00); mix(r10, g.w10); mix(r01, g.w01); mix(r11, g.w11);
    }

    __shared__ float red[SL][C][PPB];
#pragma unroll
    for (int c = 0; c < C; ++c) red[s][c][p] = acc[c];
    __syncthreads();

    float* ob = out + (size_t)(b * L + t) * C * HW + pix;
#pragma unroll
    for (int cc = s; cc < C; cc += SL) {
        float vsum = red[0][cc][p] + red[1][cc][p] + red[2][cc][p] + red[3][cc][p];
        ob[(size_t)cc * HW] = vsum;
    }
}

// ---------------------------------------------------------------------------
// Kernel 3 (fallback): R3's channel-last fp16 version (ws too small for quads).
// ---------------------------------------------------------------------------
__global__ void warp_scan_half(const float* __restrict__ cum2,
                               const __half* __restrict__ imgH,
                               float* __restrict__ out) {
    const int p   = threadIdx.x & (PPB - 1);
    const int s   = threadIdx.x >> 6;
    const int pix = blockIdx.x * PPB + p;
    const int t   = L - 1 - blockIdx.y;
    const int b   = blockIdx.z;
    const int w   = pix % W;
    const int h   = pix / W;

    const float base_gx_p1 = (2 * w + 1) * (1.0f / W);
    const float base_gy    = (2 * h + 1) * (1.0f / H) - 1.0f;

    const float* cb = cum2 + ((size_t)b * L * HW + pix) * 2;
    const float2 ct = *reinterpret_cast<const float2*>(cb + (size_t)t * HW * 2);
    const float ctx = ct.x, cty = ct.y;

    float acc[C];
#pragma unroll
    for (int c = 0; c < C; ++c) acc[c] = 0.0f;

    for (int k = s; k <= t; k += SL) {
        const float2 ck = *reinterpret_cast<const float2*>(cb + (size_t)k * HW * 2);
        SampleGeom g = sample_geom(base_gx_p1, base_gy, ctx - ck.x, cty - ck.y);

        int x0 = min(max(g.x0, 0), W - 1);
        int x1 = min(max(g.x0 + 1, 0), W - 1);
        int y0 = min(max(g.y0, 0), H - 1);
        int y1 = min(max(g.y0 + 1, 0), H - 1);

        const __half* base = imgH + ((size_t)(b * L + k) * HW) * C;
        auto tap = [&](int y, int x, float wgt) {
            float4 raw = *reinterpret_cast<const float4*>(base + (size_t)(y * W + x) * C);
            const __half2* hc = reinterpret_cast<const __half2*>(&raw);
#pragma unroll
            for (int c = 0; c < 4; ++c) {
                float2 f = __half22float2(hc[c]);
                acc[2 * c]     += wgt * f.x;
                acc[2 * c + 1] += wgt * f.y;
            }
        };
        tap(y0, x0, g.w00);
        tap(y0, x1, g.w10);
        tap(y1, x0, g.w01);
        tap(y1, x1, g.w11);
    }

    __shared__ float red[SL][C][PPB];
#pragma unroll
    for (int c = 0; c < C; ++c) red[s][c][p] = acc[c];
    __syncthreads();

    float* ob = out + (size_t)(b * L + t) * C * HW + pix;
#pragma unroll
    for (int cc = s; cc < C; cc += SL) {
        float vsum = red[0][cc][p] + red[1][cc][p] + red[2][cc][p] + red[3][cc][p];
        ob[(size_t)cc * HW] = vsum;
    }
}

// ---------------------------------------------------------------------------
extern "C" void kernel_launch(void* const* d_in, const int* in_sizes, int n_in,
                              void* d_out, int out_size, void* d_ws, size_t ws_size,
                              hipStream_t stream) {
    const float* flows  = (const float*)d_in[0];   // (B, L, 2, H, W) fp32
    const float* images = (const float*)d_in[1];   // (B, L, C, H, W) fp32
    float* out = (float*)d_out;                    // (B, L, C, H, W) fp32

    const size_t cum_elems  = (size_t)B * L * 2 * HW;          // 1.77 MB
    const size_t quad_bytes = (size_t)B * L * QN * 32 * 2;     // 14.75 MB
    const size_t need_quad  = cum_elems * 4 + quad_bytes;      // 16.5 MB

    float* cum2 = (float*)d_ws;

    cumsum_kernel<<<(B * 2 * HW + 255) / 256, 256, 0, stream>>>(flows, cum2);

    dim3 grid(HW / PPB, L, B);
    if (ws_size >= need_quad) {
        __half* quads = (__half*)(cum2 + cum_elems);
        quad_build_kernel<<<(B * L * QN + 255) / 256, 256, 0, stream>>>(images, quads);
        warp_scan_quad<<<grid, 256, 0, stream>>>(cum2, quads, out);
    } else {
        __half* imgH = (__half*)(cum2 + cum_elems);
        convert_kernel<<<(B * L * HW + 255) / 256, 256, 0, stream>>>(images, imgH);
        warp_scan_half<<<grid, 256, 0, stream>>>(cum2, imgH, out);
    }
}

// Round 6
// 59.122 us; speedup vs baseline: 1.2389x; 1.2389x over previous
//
#include <hip/hip_runtime.h>
#include <hip/hip_fp16.h>

// Problem constants (B, L, C, H, W) = (2, 48, 8, 48, 48)
constexpr int B = 2, L = 48, C = 8, H = 48, W = 48;
constexpr int HW = H * W;   // 2304

constexpr int PPB = 32;     // pixels per block
constexpr int SL  = 8;      // k-slices per block (threads = PPB*SL = 256)

constexpr int NCUM        = B * 2 * HW;               // 9216 cumsum threads
constexpr int CUM_BLOCKS  = NCUM / 256;               // 36
constexpr int NCONV       = B * L * HW;               // 221184 convert threads
constexpr int CONV_BLOCKS = (NCONV + 255) / 256;      // 864

// ---------------------------------------------------------------------------
// Prep kernel (fused): blocks [0, CUM_BLOCKS) do the flow cumsum (long serial
// scan -> launch first); remaining blocks convert images to fp16 channel-last.
// cum2 layout (B, L, HW, 2) float32; imgH layout (B, L, HW, C) fp16.
// ---------------------------------------------------------------------------
__global__ void prep_kernel(const float* __restrict__ flows,
                            const float* __restrict__ images,
                            float* __restrict__ cum2,
                            __half* __restrict__ imgH) {
    if (blockIdx.x < CUM_BLOCKS) {
        int tid  = blockIdx.x * 256 + threadIdx.x;     // < NCUM
        int pix  = tid % HW;
        int comp = (tid / HW) & 1;
        int b    = tid / (2 * HW);
        const float* src = flows + (size_t)b * L * 2 * HW + (size_t)comp * HW + pix;
        float*       dst = cum2  + ((size_t)b * L * HW + pix) * 2 + comp;
        float acc = 0.0f;
#pragma unroll
        for (int l = 0; l < L; ++l) {
            acc += src[(size_t)l * 2 * HW];
            dst[(size_t)l * HW * 2] = acc;
        }
    } else {
        int tid = (blockIdx.x - CUM_BLOCKS) * 256 + threadIdx.x;
        if (tid >= NCONV) return;
        int pix = tid % HW;
        int bl  = tid / HW;
        const float* src = images + (size_t)bl * C * HW + pix;
        __half h[C];
#pragma unroll
        for (int c = 0; c < C; ++c) h[c] = __float2half(src[(size_t)c * HW]);
        float4* dst = reinterpret_cast<float4*>(imgH + ((size_t)bl * HW + pix) * C);
        *dst = *reinterpret_cast<float4*>(h);
    }
}

// ---------------------------------------------------------------------------
// Per-sample coordinate math (exact wrap ladder, matches jnp.remainder for
// |v| < 8; tap validity on UNCLAMPED floored coords, matching the reference).
// ---------------------------------------------------------------------------
struct SampleGeom {
    float w00, w10, w01, w11;
    int x0, y0;     // unclamped floor corner; y0 is UNBOUNDED (y not wrapped)
};

__device__ __forceinline__ SampleGeom sample_geom(float base_gx_p1, float base_gy,
                                                  float relx, float rely) {
    float v = base_gx_p1 + relx;
    v = (v >= 2.0f) ? v - 2.0f : v;
    v = (v >= 2.0f) ? v - 2.0f : v;
    v = (v >= 2.0f) ? v - 2.0f : v;
    v = (v <  0.0f) ? v + 2.0f : v;
    v = (v <  0.0f) ? v + 2.0f : v;
    v = (v <  0.0f) ? v + 2.0f : v;

    float ix = (v * (float)W - 1.0f) * 0.5f;              // [-0.5, 47.5)
    float gy = base_gy + rely;
    float iy = ((gy + 1.0f) * (float)H - 1.0f) * 0.5f;

    float x0f = floorf(ix), y0f = floorf(iy);
    float wx1 = ix - x0f,   wy1 = iy - y0f;
    float wx0 = 1.0f - wx1, wy0 = 1.0f - wy1;

    float vx0 = (x0f >= 0.0f  && x0f <= (float)(W - 1)) ? 1.0f : 0.0f;
    float vx1 = (x0f >= -1.0f && x0f <= (float)(W - 2)) ? 1.0f : 0.0f;
    float vy0 = (y0f >= 0.0f  && y0f <= (float)(H - 1)) ? 1.0f : 0.0f;
    float vy1 = (y0f >= -1.0f && y0f <= (float)(H - 2)) ? 1.0f : 0.0f;

    SampleGeom g;
    g.w00 = wx0 * wy0 * vx0 * vy0;
    g.w10 = wx1 * wy0 * vx1 * vy0;
    g.w01 = wx0 * wy1 * vx0 * vy1;
    g.w11 = wx1 * wy1 * vx1 * vy1;
    g.x0  = (int)x0f;
    g.y0  = (int)y0f;
    return g;
}

__device__ __forceinline__ float4 tap_load(const __half* __restrict__ base, int y, int x) {
    return *reinterpret_cast<const float4*>(base + (size_t)(y * W + x) * C);
}

__device__ __forceinline__ void tap_mix(float acc[C], const float4& raw, float wgt) {
    const __half2* hc = reinterpret_cast<const __half2*>(&raw);
#pragma unroll
    for (int c = 0; c < 4; ++c) {
        float2 f = __half22float2(hc[c]);
        acc[2 * c]     += wgt * f.x;
        acc[2 * c + 1] += wgt * f.y;
    }
}

// ---------------------------------------------------------------------------
// Main warp+scan. Block = 256 threads = 32 pixels x 8 k-slices.
// cum for the block's 32 pixels x 48 k staged in LDS (12 KB) so tap-load
// addresses depend only on an LDS read. k-loop 2-stage: all 8 tap loads of
// two samples issued before any consumption (keeps ~8 VMEM requests in
// flight per wave; the per-CU lane-request rate ~1/cyc is the wall).
// Tap indices are DOUBLE-SIDED clamped (y0 is unbounded!); zero validity
// weights neutralize the clamped taps, matching the reference. (R5's NaN bug
// was one-sided clamps -> OOB reads -> 0 * NaN = NaN.)
// grid = (72, 48, 2) = 6912 blocks; t = L-1-blockIdx.y (heavy blocks first).
// ---------------------------------------------------------------------------
__global__ __launch_bounds__(256) void warp_scan_kernel(const float* __restrict__ cum2,
                                                        const __half* __restrict__ imgH,
                                                        float* __restrict__ out) {
    const int p    = threadIdx.x & (PPB - 1);   // pixel lane 0..31
    const int s    = threadIdx.x / PPB;         // k-slice 0..7
    const int pix0 = blockIdx.x * PPB;
    const int pix  = pix0 + p;
    const int t    = L - 1 - blockIdx.y;
    const int b    = blockIdx.z;
    const int w    = pix % W;
    const int h    = pix / W;

    const float base_gx_p1 = (2 * w + 1) * (1.0f / W);
    const float base_gy    = (2 * h + 1) * (1.0f / H) - 1.0f;

    // stage cum (48 k x 32 px x 2 comps) into LDS, coalesced
    __shared__ float cumS[L][PPB][2];           // 12 KB
    {
        const float* gsrc = cum2 + ((size_t)b * L * HW + pix0) * 2;
        for (int i = threadIdx.x; i < L * PPB * 2; i += 256) {
            int rem = i & (PPB * 2 - 1);        // (pp, comp) packed
            int k   = i / (PPB * 2);
            cumS[k][rem >> 1][rem & 1] = gsrc[(size_t)k * HW * 2 + rem];
        }
    }
    __syncthreads();

    const float ctx = cumS[t][p][0];
    const float cty = cumS[t][p][1];

    float acc[C];
#pragma unroll
    for (int c = 0; c < C; ++c) acc[c] = 0.0f;

    const __half* imgb = imgH + (size_t)b * L * HW * C;

    for (int k = s; k <= t; k += 2 * SL) {
        // ---- stage 0: geometry + issue 4 loads
        SampleGeom g0 = sample_geom(base_gx_p1, base_gy,
                                    ctx - cumS[k][p][0], cty - cumS[k][p][1]);
        const __half* b0 = imgb + (size_t)k * HW * C;
        int x00 = min(max(g0.x0,     0), W - 1);
        int x01 = min(max(g0.x0 + 1, 0), W - 1);
        int y00 = min(max(g0.y0,     0), H - 1);
        int y01 = min(max(g0.y0 + 1, 0), H - 1);
        float4 r00 = tap_load(b0, y00, x00);
        float4 r01 = tap_load(b0, y00, x01);
        float4 r02 = tap_load(b0, y01, x00);
        float4 r03 = tap_load(b0, y01, x01);

        // ---- stage 1: geometry + issue 4 more loads (before consuming stage 0)
        const int  k1 = k + SL;
        const bool h1 = (k1 <= t);
        SampleGeom g1;
        float4 r10, r11, r12, r13;
        if (h1) {
            g1 = sample_geom(base_gx_p1, base_gy,
                             ctx - cumS[k1][p][0], cty - cumS[k1][p][1]);
            const __half* b1 = imgb + (size_t)k1 * HW * C;
            int x10 = min(max(g1.x0,     0), W - 1);
            int x11 = min(max(g1.x0 + 1, 0), W - 1);
            int y10 = min(max(g1.y0,     0), H - 1);
            int y11 = min(max(g1.y0 + 1, 0), H - 1);
            r10 = tap_load(b1, y10, x10);
            r11 = tap_load(b1, y10, x11);
            r12 = tap_load(b1, y11, x10);
            r13 = tap_load(b1, y11, x11);
        }

        // ---- consume
        tap_mix(acc, r00, g0.w00);
        tap_mix(acc, r01, g0.w10);
        tap_mix(acc, r02, g0.w01);
        tap_mix(acc, r03, g0.w11);
        if (h1) {
            tap_mix(acc, r10, g1.w00);
            tap_mix(acc, r11, g1.w10);
            tap_mix(acc, r12, g1.w01);
            tap_mix(acc, r13, g1.w11);
        }
    }

    // reduce the 8 k-slices via LDS: red[slice][ch][pix] (8 KB)
    __shared__ float red[SL][C][PPB];
#pragma unroll
    for (int c = 0; c < C; ++c) red[s][c][p] = acc[c];
    __syncthreads();

    // 256 threads -> 256 outputs: thread (s,p) owns channel s
    float vsum = 0.0f;
#pragma unroll
    for (int j = 0; j < SL; ++j) vsum += red[j][s][p];
    out[((size_t)(b * L + t) * C + s) * HW + pix] = vsum;
}

// ---------------------------------------------------------------------------
extern "C" void kernel_launch(void* const* d_in, const int* in_sizes, int n_in,
                              void* d_out, int out_size, void* d_ws, size_t ws_size,
                              hipStream_t stream) {
    const float* flows  = (const float*)d_in[0];   // (B, L, 2, H, W) fp32
    const float* images = (const float*)d_in[1];   // (B, L, C, H, W) fp32
    float* out = (float*)d_out;                    // (B, L, C, H, W) fp32

    const size_t cum_elems = (size_t)B * L * 2 * HW;   // 442,368 floats (1.77 MB)

    float*  cum2 = (float*)d_ws;
    __half* imgH = (__half*)(cum2 + cum_elems);        // 3.54 MB fp16 channel-last

    prep_kernel<<<CUM_BLOCKS + CONV_BLOCKS, 256, 0, stream>>>(flows, images, cum2, imgH);

    dim3 grid(HW / PPB, L, B);
    warp_scan_kernel<<<grid, 256, 0, stream>>>(cum2, imgH, out);
}

// Round 7
// 56.798 us; speedup vs baseline: 1.2896x; 1.0409x over previous
//
#include <hip/hip_runtime.h>
#include <hip/hip_fp16.h>
#include <stdint.h>

// Problem constants (B, L, C, H, W) = (2, 48, 8, 48, 48)
constexpr int B = 2, L = 48, C = 8, H = 48, W = 48;
constexpr int HW = H * W;   // 2304

constexpr int CPX    = 256;        // pixels per chunk (== threads per block)
constexpr int CHUNKS = HW / CPX;   // 9
constexpr int NPAIR  = L / 2;      // 24 pairs {g, 47-g}: 49 sample-k per pixel, uniform

constexpr int NCUM        = B * 2 * HW;               // 9216 cumsum threads
constexpr int CUM_BLOCKS  = NCUM / 256;               // 36
constexpr int NCONV       = B * L * HW;               // 221184 convert threads
constexpr int CONV_BLOCKS = (NCONV + 255) / 256;      // 864

// ---------------------------------------------------------------------------
// Prep kernel (fused, unchanged from R6): cumsum of flows -> cum2 (B,L,HW,2)
// fp32 (same accumulation order as jnp.cumsum), and images -> fp16
// channel-last imgH (B,L,HW,C).
// ---------------------------------------------------------------------------
__global__ void prep_kernel(const float* __restrict__ flows,
                            const float* __restrict__ images,
                            float* __restrict__ cum2,
                            __half* __restrict__ imgH) {
    if (blockIdx.x < CUM_BLOCKS) {
        int tid  = blockIdx.x * 256 + threadIdx.x;     // < NCUM
        int pix  = tid % HW;
        int comp = (tid / HW) & 1;
        int b    = tid / (2 * HW);
        const float* src = flows + (size_t)b * L * 2 * HW + (size_t)comp * HW + pix;
        float*       dst = cum2  + ((size_t)b * L * HW + pix) * 2 + comp;
        float acc = 0.0f;
#pragma unroll
        for (int l = 0; l < L; ++l) {
            acc += src[(size_t)l * 2 * HW];
            dst[(size_t)l * HW * 2] = acc;
        }
    } else {
        int tid = (blockIdx.x - CUM_BLOCKS) * 256 + threadIdx.x;
        if (tid >= NCONV) return;
        int pix = tid % HW;
        int bl  = tid / HW;
        const float* src = images + (size_t)bl * C * HW + pix;
        __half h[C];
#pragma unroll
        for (int c = 0; c < C; ++c) h[c] = __float2half(src[(size_t)c * HW]);
        float4* dst = reinterpret_cast<float4*>(imgH + ((size_t)bl * HW + pix) * C);
        *dst = *reinterpret_cast<float4*>(h);
    }
}

// ---------------------------------------------------------------------------
// Per-sample coordinate math (exact wrap ladder, matches jnp.remainder for
// |v| < 8; tap validity on UNCLAMPED floored coords, matching the reference).
// ---------------------------------------------------------------------------
struct SampleGeom {
    float w00, w10, w01, w11;
    int x0, y0;     // unclamped floor corner; y0 is UNBOUNDED (y not wrapped)
};

__device__ __forceinline__ SampleGeom sample_geom(float base_gx_p1, float base_gy,
                                                  float relx, float rely) {
    float v = base_gx_p1 + relx;
    v = (v >= 2.0f) ? v - 2.0f : v;
    v = (v >= 2.0f) ? v - 2.0f : v;
    v = (v >= 2.0f) ? v - 2.0f : v;
    v = (v <  0.0f) ? v + 2.0f : v;
    v = (v <  0.0f) ? v + 2.0f : v;
    v = (v <  0.0f) ? v + 2.0f : v;

    float ix = (v * (float)W - 1.0f) * 0.5f;              // [-0.5, 47.5)
    float gy = base_gy + rely;
    float iy = ((gy + 1.0f) * (float)H - 1.0f) * 0.5f;

    float x0f = floorf(ix), y0f = floorf(iy);
    float wx1 = ix - x0f,   wy1 = iy - y0f;
    float wx0 = 1.0f - wx1, wy0 = 1.0f - wy1;

    float vx0 = (x0f >= 0.0f  && x0f <= (float)(W - 1)) ? 1.0f : 0.0f;
    float vx1 = (x0f >= -1.0f && x0f <= (float)(W - 2)) ? 1.0f : 0.0f;
    float vy0 = (y0f >= 0.0f  && y0f <= (float)(H - 1)) ? 1.0f : 0.0f;
    float vy1 = (y0f >= -1.0f && y0f <= (float)(H - 2)) ? 1.0f : 0.0f;

    SampleGeom g;
    g.w00 = wx0 * wy0 * vx0 * vy0;
    g.w10 = wx1 * wy0 * vx1 * vy0;
    g.w01 = wx0 * wy1 * vx0 * vy1;
    g.w11 = wx1 * wy1 * vx1 * vy1;
    g.x0  = (int)x0f;
    g.y0  = (int)y0f;
    return g;
}

// ---------------------------------------------------------------------------
// Stage one fp16 frame (2304 records x 16B = 36.9 KB) global -> LDS.
// Linear layout: record r -> lds_base + r*16B; per wave this is the
// wave-uniform-base + lane*16 pattern global_load_lds requires.
// ---------------------------------------------------------------------------
#if defined(__has_builtin)
#if __has_builtin(__builtin_amdgcn_global_load_lds)
#define HAVE_GLD_LDS 1
#endif
#endif

__device__ __forceinline__ void stage_frame(const __half* __restrict__ gsrc,
                                            __half* lds_base, int tid) {
#ifdef HAVE_GLD_LDS
#pragma unroll
    for (int i = 0; i < 9; ++i) {
        const int r = i * 256 + tid;
        __builtin_amdgcn_global_load_lds(
            (const __attribute__((address_space(1))) void*)(gsrc + (size_t)r * C),
            (__attribute__((address_space(3))) void*)(lds_base + (size_t)r * C),
            16, 0, 0);
    }
#else
#pragma unroll
    for (int i = 0; i < 9; ++i) {
        const int r = i * 256 + tid;
        float4 v = *reinterpret_cast<const float4*>(gsrc + (size_t)r * C);
        *reinterpret_cast<float4*>(lds_base + (size_t)r * C) = v;
    }
#endif
}

// ---------------------------------------------------------------------------
// Gather 4 taps from the LDS frame and accumulate 8 channels.
// Indices double-sided clamped (y0 unbounded); zero validity weights
// neutralize clamped taps (0 * finite LDS data — no NaN possible).
// ---------------------------------------------------------------------------
__device__ __forceinline__ void gather_mix(const __half* fb, const SampleGeom& g,
                                           float acc[C]) {
    int x0 = min(max(g.x0,     0), W - 1);
    int x1 = min(max(g.x0 + 1, 0), W - 1);
    int y0 = min(max(g.y0,     0), H - 1);
    int y1 = min(max(g.y0 + 1, 0), H - 1);
    float4 r00 = *reinterpret_cast<const float4*>(fb + (y0 * W + x0) * C);
    float4 r10 = *reinterpret_cast<const float4*>(fb + (y0 * W + x1) * C);
    float4 r01 = *reinterpret_cast<const float4*>(fb + (y1 * W + x0) * C);
    float4 r11 = *reinterpret_cast<const float4*>(fb + (y1 * W + x1) * C);
    auto mix = [&](const float4& raw, float wgt) {
        const __half2* hc = reinterpret_cast<const __half2*>(&raw);
#pragma unroll
        for (int c = 0; c < 4; ++c) {
            float2 f = __half22float2(hc[c]);
            acc[2 * c]     += wgt * f.x;
            acc[2 * c + 1] += wgt * f.y;
        }
    };
    mix(r00, g.w00); mix(r10, g.w10); mix(r01, g.w01); mix(r11, g.w11);
}

// ---------------------------------------------------------------------------
// Main kernel: LDS-gather pscan.
// Block = (chunk, pair g, b); 256 threads, 1 pixel each; handles BOTH
// t1 = g and t2 = 47-g (exactly 49 sample-k per pixel -> uniform blocks).
// k-loop (k = 0..t2) stages frame k+1 into the spare LDS buffer (async,
// global_load_lds) while gathering frame k from the current buffer via
// ds_read_b128. One __syncthreads per k (its vmcnt(0)+lgkmcnt(0) drain
// makes the staged buffer visible and protects the buffer swap).
// grid = (9, 24, 2) = 432 equal blocks; LDS 73.7 KB -> 2 blocks/CU, all
// co-resident; inter-block overlap hides the barrier drain.
// ---------------------------------------------------------------------------
__global__ __launch_bounds__(256) void scan_lds_kernel(const float* __restrict__ cum2,
                                                       const __half* __restrict__ imgH,
                                                       float* __restrict__ out) {
    const int tid = threadIdx.x;
    const int pix = blockIdx.x * CPX + tid;
    const int g   = blockIdx.y;
    const int b   = blockIdx.z;
    const int t1 = g, t2 = L - 1 - g;
    const int kmax = t2;

    const int w = pix % W;
    const int h = pix / W;
    const float base_gx_p1 = (2 * w + 1) * (1.0f / W);
    const float base_gy    = (2 * h + 1) * (1.0f / H) - 1.0f;

    __shared__ __align__(16) __half frame[2][HW * C];   // 2 x 36.9 KB

    const float* cb = cum2 + ((size_t)b * L * HW + pix) * 2;
    const float2 c1 = *reinterpret_cast<const float2*>(cb + (size_t)t1 * HW * 2);
    const float2 c2 = *reinterpret_cast<const float2*>(cb + (size_t)t2 * HW * 2);

    float acc1[C], acc2[C];
#pragma unroll
    for (int c = 0; c < C; ++c) { acc1[c] = 0.0f; acc2[c] = 0.0f; }

    const __half* gb = imgH + (size_t)b * L * HW * C;

    stage_frame(gb, frame[0], tid);                       // frame k=0 -> buf0
    float2 ck = *reinterpret_cast<const float2*>(cb);     // cum[k=0]
    __syncthreads();                                      // staging visible

    int cur = 0;
    for (int k = 0; k <= kmax; ++k) {
        // issue next frame's staging into the spare buffer (overlaps gather)
        if (k < kmax)
            stage_frame(gb + (size_t)(k + 1) * HW * C, frame[cur ^ 1], tid);
        // prefetch next k's cum
        float2 ckn = ck;
        if (k < kmax)
            ckn = *reinterpret_cast<const float2*>(cb + (size_t)(k + 1) * HW * 2);

        const __half* fb = frame[cur];

        // sample for t2 (always active: k <= kmax == t2)
        {
            SampleGeom gm = sample_geom(base_gx_p1, base_gy, c2.x - ck.x, c2.y - ck.y);
            gather_mix(fb, gm, acc2);
        }
        // sample for t1 (block-uniform condition)
        if (k <= t1) {
            SampleGeom gm = sample_geom(base_gx_p1, base_gy, c1.x - ck.x, c1.y - ck.y);
            gather_mix(fb, gm, acc1);
        }

        ck = ckn;
        __syncthreads();    // gathers done + next staging landed -> safe swap
        cur ^= 1;
    }

    float* o1 = out + (size_t)(b * L + t1) * C * HW + pix;
    float* o2 = out + (size_t)(b * L + t2) * C * HW + pix;
#pragma unroll
    for (int c = 0; c < C; ++c) {
        o1[(size_t)c * HW] = acc1[c];
        o2[(size_t)c * HW] = acc2[c];
    }
}

// ---------------------------------------------------------------------------
extern "C" void kernel_launch(void* const* d_in, const int* in_sizes, int n_in,
                              void* d_out, int out_size, void* d_ws, size_t ws_size,
                              hipStream_t stream) {
    const float* flows  = (const float*)d_in[0];   // (B, L, 2, H, W) fp32
    const float* images = (const float*)d_in[1];   // (B, L, C, H, W) fp32
    float* out = (float*)d_out;                    // (B, L, C, H, W) fp32

    const size_t cum_elems = (size_t)B * L * 2 * HW;   // 1.77 MB

    float*  cum2 = (float*)d_ws;
    __half* imgH = (__half*)(cum2 + cum_elems);        // 3.54 MB fp16 channel-last

    prep_kernel<<<CUM_BLOCKS + CONV_BLOCKS, 256, 0, stream>>>(flows, images, cum2, imgH);

    dim3 grid(CHUNKS, NPAIR, B);                       // (9, 24, 2) = 432 blocks
    scan_lds_kernel<<<grid, 256, 0, stream>>>(cum2, imgH, out);
}